// Round 14
// baseline (551.039 us; speedup 1.0000x reference)
//
#include <hip/hip_runtime.h>

#define BB 128
#define NN 512
#define DD 128

// ---------------- kernel 1: h -> normalized hn ----------------
__global__ __launch_bounds__(256) void hn_kernel(const float* __restrict__ h,
                                                 const float* __restrict__ W0,
                                                 const float* __restrict__ W1,
                                                 float* __restrict__ hn) {
    int wave = (int)((blockIdx.x * blockDim.x + threadIdx.x) >> 6);  // 0..B*N-1
    int lane = threadIdx.x & 63;
    const float2* h2 = (const float2*)(h + (size_t)wave * DD);
    float2 w0 = ((const float2*)W0)[lane];
    float2 w1 = ((const float2*)W1)[lane];
    float2 x = h2[lane];
    float p0 = fmaxf(x.x * w0.x, 0.0f) * w1.x;
    float p1 = fmaxf(x.y * w0.y, 0.0f) * w1.y;
    float ss = p0 * p0 + p1 * p1;
#pragma unroll
    for (int m = 32; m; m >>= 1) ss += __shfl_xor(ss, m);
    float inv = 1.0f / (sqrtf(ss) + 1e-12f);
    float2 o;
    o.x = p0 * inv;
    o.y = p1 * inv;
    ((float2*)(hn + (size_t)wave * DD))[lane] = o;
}

// ---------------- kernel 2: K = exp(2*(hn hn^T + eye) - 2), persistent -----
#define KC 32
__global__ __launch_bounds__(256) void sim_kernel(const float* __restrict__ hn,
                                                  const int* __restrict__ lengths,
                                                  float* __restrict__ K) {
    __shared__ float As[KC][132];
    __shared__ float Bs[KC][132];
    __shared__ int pre[BB + 1];  // prefix sum of per-batch tile counts
    int tid = threadIdx.x;
    if (tid == 0) {
        int acc = 0;
        for (int b = 0; b < BB; b++) {
            pre[b] = acc;
            int len = max(lengths[b], 1);
            int nt = (len + 127) >> 7;
            acc += nt * nt;
        }
        pre[BB] = acc;
    }
    __syncthreads();
    int total = pre[BB];

    int lr = tid >> 3;
    int lk = (tid & 7) << 2;
    int tx = tid & 15, ty = tid >> 4;

    for (int t = blockIdx.x; t < total; t += gridDim.x) {
        int lo = 0, hi = BB;
        while (lo + 1 < hi) {
            int mid = (lo + hi) >> 1;
            if (pre[mid] <= t) lo = mid; else hi = mid;
        }
        int b = lo;
        int local = t - pre[b];
        int len = max(lengths[b], 1);
        int nt = (len + 127) >> 7;
        int ti = local / nt;
        int tj = local - ti * nt;
        int r0 = ti << 7, c0 = tj << 7;
        const float* base = hn + (size_t)b * NN * DD;
        float acc[8][8] = {};

        for (int kc = 0; kc < DD; kc += KC) {
#pragma unroll
            for (int rr = 0; rr < 128; rr += 32) {
                float4 a = *(const float4*)(base + (size_t)(r0 + lr + rr) * DD + kc + lk);
                As[lk + 0][lr + rr] = a.x; As[lk + 1][lr + rr] = a.y;
                As[lk + 2][lr + rr] = a.z; As[lk + 3][lr + rr] = a.w;
                float4 bb = *(const float4*)(base + (size_t)(c0 + lr + rr) * DD + kc + lk);
                Bs[lk + 0][lr + rr] = bb.x; Bs[lk + 1][lr + rr] = bb.y;
                Bs[lk + 2][lr + rr] = bb.z; Bs[lk + 3][lr + rr] = bb.w;
            }
            __syncthreads();
#pragma unroll
            for (int kk = 0; kk < KC; kk++) {
                float4 a0 = *(const float4*)&As[kk][ty * 8];
                float4 a1 = *(const float4*)&As[kk][ty * 8 + 4];
                float4 b0 = *(const float4*)&Bs[kk][tx * 4];
                float4 b1 = *(const float4*)&Bs[kk][64 + tx * 4];
                float ar[8] = {a0.x, a0.y, a0.z, a0.w, a1.x, a1.y, a1.z, a1.w};
                float bc[8] = {b0.x, b0.y, b0.z, b0.w, b1.x, b1.y, b1.z, b1.w};
#pragma unroll
                for (int r = 0; r < 8; r++)
#pragma unroll
                    for (int c = 0; c < 8; c++)
                        acc[r][c] = fmaf(ar[r], bc[c], acc[r][c]);
            }
            __syncthreads();
        }
        float* out = K + (size_t)b * NN * NN;
#pragma unroll
        for (int r = 0; r < 8; r++) {
            int i = r0 + ty * 8 + r;
            if (i >= len) continue;
#pragma unroll
            for (int cg = 0; cg < 2; cg++) {
                int j0 = c0 + cg * 64 + tx * 4;
                if (j0 >= len) continue;
                float vv[4];
#pragma unroll
                for (int c = 0; c < 4; c++) {
                    float s = acc[r][cg * 4 + c] + ((i == j0 + c) ? 1.0f : 0.0f);
                    vv[c] = expf(2.0f * s - 2.0f);
                }
                float4 o;
                o.x = vv[0]; o.y = vv[1]; o.z = vv[2]; o.w = vv[3];
                *(float4*)(out + (size_t)i * NN + j0) = o;
            }
        }
    }
}

__device__ __forceinline__ float dot8(float4 A, float4 B, float4 x0, float4 x1) {
    float d = fmaf(A.x, x0.x, fmaf(A.y, x0.y, fmaf(A.z, x0.z, A.w * x0.w)));
    return fmaf(B.x, x1.x, fmaf(B.y, x1.y, fmaf(B.z, x1.z, fmaf(B.w, x1.w, d))));
}

// ---------------- Sinkhorn: ONE BLOCK PER BATCH, no cross-block exchange ---
// 128 blocks x 512 thr (regular launch; R6's 512-thr failure was the coop
// validator, now unused). Each block owns its whole batch: 8 waves, wave w
// handles rows r == w,w+8,w+16,w+24 (mod 32) in 4-row groups. Column sums
// reduce through 16 KB LDS + __syncthreads — the R5..R13 slot/tag protocol
// (agent-scope stores + IF$ round-trip polling, several us/iter) is GONE.
// Accumulation order changes vs R13 — deliberate test of whether the
// threshold-flip failure mode is real (R6-R10 forensics say those were all
// silent coop-launch rejections, never numeric flips; absmax was 0.0 in
// every passing round).
__global__ __launch_bounds__(512) void sink1_kernel(const float* __restrict__ K,
                                                    float* __restrict__ u_buf,
                                                    float* __restrict__ v_buf,
                                                    const int* __restrict__ lengths) {
    __shared__ float xb[NN];      // current multiplier vector (v)
    __shared__ float pv[8 * NN];  // per-wave column partials (16 KB)

    int b = blockIdx.x;
    int len = max(lengths[b], 1);
    int len4 = (len + 3) & ~3;
    float inv_n = 1.0f / (float)len;

    int tid = threadIdx.x;
    int w = tid >> 6, l = tid & 63;
    int c0 = 4 * l, c1 = 256 + 4 * l;
    bool a0 = c0 < len4, a1 = c1 < len4;
    const float* Kb = K + (size_t)b * NN * NN;

    xb[tid] = (tid < len) ? 1.0f : 0.0f;
    __syncthreads();

    for (int t = 0; t < 20; t++) {
        float4 xv0 = *(const float4*)(xb + c0);
        float4 xv1 = *(const float4*)(xb + c1);
        float4 pa = {0, 0, 0, 0}, pb = {0, 0, 0, 0};

        // ---- phase A: 4-row groups (rows i, i+8, i+16, i+24), stride 32 ----
        int i = w;
#pragma unroll 2
        for (; i + 24 < len; i += 32) {
            const float* g0 = Kb + (size_t)i * NN;
            const float* g1 = g0 + (size_t)8 * NN;
            const float* g2 = g0 + (size_t)16 * NN;
            const float* g3 = g0 + (size_t)24 * NN;
            float4 A0 = {0,0,0,0}, A1 = {0,0,0,0}, A2 = {0,0,0,0}, A3 = {0,0,0,0};
            float4 B0 = {0,0,0,0}, B1 = {0,0,0,0}, B2 = {0,0,0,0}, B3 = {0,0,0,0};
            if (a0) {
                A0 = *(const float4*)(g0 + c0); A1 = *(const float4*)(g1 + c0);
                A2 = *(const float4*)(g2 + c0); A3 = *(const float4*)(g3 + c0);
            }
            if (a1) {
                B0 = *(const float4*)(g0 + c1); B1 = *(const float4*)(g1 + c1);
                B2 = *(const float4*)(g2 + c1); B3 = *(const float4*)(g3 + c1);
            }
            float d0 = dot8(A0, B0, xv0, xv1);
            float d1 = dot8(A1, B1, xv0, xv1);
            float d2 = dot8(A2, B2, xv0, xv1);
            float d3 = dot8(A3, B3, xv0, xv1);
#pragma unroll
            for (int m = 32; m; m >>= 1) {  // 4 interleaved butterfly chains
                d0 += __shfl_xor(d0, m);
                d1 += __shfl_xor(d1, m);
                d2 += __shfl_xor(d2, m);
                d3 += __shfl_xor(d3, m);
            }
            float u0 = inv_n / (d0 + 1e-9f), u1 = inv_n / (d1 + 1e-9f);
            float u2 = inv_n / (d2 + 1e-9f), u3 = inv_n / (d3 + 1e-9f);
            pa.x = fmaf(A0.x, u0, fmaf(A1.x, u1, fmaf(A2.x, u2, fmaf(A3.x, u3, pa.x))));
            pa.y = fmaf(A0.y, u0, fmaf(A1.y, u1, fmaf(A2.y, u2, fmaf(A3.y, u3, pa.y))));
            pa.z = fmaf(A0.z, u0, fmaf(A1.z, u1, fmaf(A2.z, u2, fmaf(A3.z, u3, pa.z))));
            pa.w = fmaf(A0.w, u0, fmaf(A1.w, u1, fmaf(A2.w, u2, fmaf(A3.w, u3, pa.w))));
            pb.x = fmaf(B0.x, u0, fmaf(B1.x, u1, fmaf(B2.x, u2, fmaf(B3.x, u3, pb.x))));
            pb.y = fmaf(B0.y, u0, fmaf(B1.y, u1, fmaf(B2.y, u2, fmaf(B3.y, u3, pb.y))));
            pb.z = fmaf(B0.z, u0, fmaf(B1.z, u1, fmaf(B2.z, u2, fmaf(B3.z, u3, pb.z))));
            pb.w = fmaf(B0.w, u0, fmaf(B1.w, u1, fmaf(B2.w, u2, fmaf(B3.w, u3, pb.w))));
            if (t == 19 && l == 0) {
                float* ub = u_buf + (size_t)b * NN;
                ub[i] = u0; ub[i + 8] = u1; ub[i + 16] = u2; ub[i + 24] = u3;
            }
        }
        for (; i < len; i += 8) {  // remainder rows (same residue set mod 32)
            const float* g0 = Kb + (size_t)i * NN;
            float4 A = {0,0,0,0}, B = {0,0,0,0};
            if (a0) A = *(const float4*)(g0 + c0);
            if (a1) B = *(const float4*)(g0 + c1);
            float d = dot8(A, B, xv0, xv1);
#pragma unroll
            for (int m = 32; m; m >>= 1) d += __shfl_xor(d, m);
            float uu = inv_n / (d + 1e-9f);
            pa.x = fmaf(A.x, uu, pa.x); pa.y = fmaf(A.y, uu, pa.y);
            pa.z = fmaf(A.z, uu, pa.z); pa.w = fmaf(A.w, uu, pa.w);
            pb.x = fmaf(B.x, uu, pb.x); pb.y = fmaf(B.y, uu, pb.y);
            pb.z = fmaf(B.z, uu, pb.z); pb.w = fmaf(B.w, uu, pb.w);
            if (t == 19 && l == 0) u_buf[(size_t)b * NN + i] = uu;
        }

        // ---- phase B+C: block-local column reduce (LDS), new v ----
        *(float4*)(pv + w * NN + c0) = pa;
        *(float4*)(pv + w * NN + c1) = pb;
        __syncthreads();
        int c = tid;  // one column per thread
        float s = pv[c] + pv[NN + c] + pv[2 * NN + c] + pv[3 * NN + c] +
                  pv[4 * NN + c] + pv[5 * NN + c] + pv[6 * NN + c] + pv[7 * NN + c];
        float v0 = (c < len) ? (inv_n / (s + 1e-9f)) : 0.0f;
        if (t < 19) {
            xb[c] = v0;
        } else {
            v_buf[(size_t)b * NN + c] = v0;
        }
        __syncthreads();
    }
}

// ---------------- kernel 4: fused epilogue, in-place on d_out -------------
__global__ __launch_bounds__(256) void epi_kernel(float* __restrict__ io,
                                                  const float* __restrict__ u,
                                                  const float* __restrict__ v,
                                                  const int* __restrict__ lengths) {
    const float E5 = 0.006737946999085467f;  // exp(-5)
    size_t idx = (size_t)blockIdx.x * 256 + threadIdx.x;  // float4 index
    int b = (int)(idx >> 16);
    int r = (int)(idx >> 7) & (NN - 1);
    int c4 = ((int)idx & 127) << 2;
    int len = max(lengths[b], 1);
    float4 o;
    if (r >= len || c4 >= len) {
        o.x = E5; o.y = E5; o.z = E5; o.w = E5;
        ((float4*)io)[idx] = o;
        return;
    }
    float4 k = ((float4*)io)[idx];
    float ui = u[(size_t)b * NN + r];
    float4 vv = *(const float4*)(v + (size_t)b * NN + c4);
    float t = (float)len * ui;
    float kv[4] = {k.x, k.y, k.z, k.w};
    float vj[4] = {vv.x, vv.y, vv.z, vv.w};
    float ov[4];
#pragma unroll
    for (int c = 0; c < 4; c++) {
        float Kc = kv[c];
        float P = t * Kc * vj[c];
        bool valid = (c4 + c) < len;
        if (valid && P > 0.1f) {
            float x = 2.5f * logf(Kc);  // == 5*sim - 5
            ov[c] = (x > 0.0f) ? (x + 1.0f) : expf(x);
        } else {
            ov[c] = E5;
        }
    }
    o.x = ov[0]; o.y = ov[1]; o.z = ov[2]; o.w = ov[3];
    ((float4*)io)[idx] = o;
}

extern "C" void kernel_launch(void* const* d_in, const int* in_sizes, int n_in,
                              void* d_out, int out_size, void* d_ws, size_t ws_size,
                              hipStream_t stream) {
    const float* h = (const float*)d_in[0];
    const float* W0 = (const float*)d_in[1];
    const float* W1 = (const float*)d_in[2];
    const int* lengths = (const int*)d_in[3];
    float* K = (float*)d_out;  // [B,N,N] K, overwritten in place by epilogue

    char* ws = (char*)d_ws;
    float* hn = (float*)ws;                               // 33.5 MB
    size_t off = (size_t)BB * NN * DD * 4;
    float* u = (float*)(ws + off);  off += (size_t)BB * NN * 4;  // 256 KB
    float* v = (float*)(ws + off);  off += (size_t)BB * NN * 4;  // 256 KB

    hn_kernel<<<BB * NN / 4, 256, 0, stream>>>(h, W0, W1, hn);
    sim_kernel<<<1024, 256, 0, stream>>>(hn, lengths, K);
    sink1_kernel<<<BB, 512, 0, stream>>>(K, u, v, lengths);
    epi_kernel<<<(unsigned)((size_t)BB * NN * NN / 4 / 256), 256, 0, stream>>>(K, u, v, lengths);
}

// Round 15
// 416.623 us; speedup vs baseline: 1.3226x; 1.3226x over previous
//
#include <hip/hip_runtime.h>

#define BB 128
#define NN 512
#define DD 128
#define SLOT_STRIDE 544  // 512 data floats + tag int at [512] + pad (2176 B)

// ---------------- kernel 1: h -> normalized hn ----------------
__global__ __launch_bounds__(256) void hn_kernel(const float* __restrict__ h,
                                                 const float* __restrict__ W0,
                                                 const float* __restrict__ W1,
                                                 float* __restrict__ hn) {
    int wave = (int)((blockIdx.x * blockDim.x + threadIdx.x) >> 6);  // 0..B*N-1
    int lane = threadIdx.x & 63;
    const float2* h2 = (const float2*)(h + (size_t)wave * DD);
    float2 w0 = ((const float2*)W0)[lane];
    float2 w1 = ((const float2*)W1)[lane];
    float2 x = h2[lane];
    float p0 = fmaxf(x.x * w0.x, 0.0f) * w1.x;
    float p1 = fmaxf(x.y * w0.y, 0.0f) * w1.y;
    float ss = p0 * p0 + p1 * p1;
#pragma unroll
    for (int m = 32; m; m >>= 1) ss += __shfl_xor(ss, m);
    float inv = 1.0f / (sqrtf(ss) + 1e-12f);
    float2 o;
    o.x = p0 * inv;
    o.y = p1 * inv;
    ((float2*)(hn + (size_t)wave * DD))[lane] = o;
}

// ---------------- kernel 2: K = exp(2*(hn hn^T + eye) - 2), persistent -----
#define KC 32
__global__ __launch_bounds__(256) void sim_kernel(const float* __restrict__ hn,
                                                  const int* __restrict__ lengths,
                                                  float* __restrict__ K) {
    __shared__ float As[KC][132];
    __shared__ float Bs[KC][132];
    __shared__ int pre[BB + 1];  // prefix sum of per-batch tile counts
    int tid = threadIdx.x;
    if (tid == 0) {
        int acc = 0;
        for (int b = 0; b < BB; b++) {
            pre[b] = acc;
            int len = max(lengths[b], 1);
            int nt = (len + 127) >> 7;
            acc += nt * nt;
        }
        pre[BB] = acc;
    }
    __syncthreads();
    int total = pre[BB];

    int lr = tid >> 3;
    int lk = (tid & 7) << 2;
    int tx = tid & 15, ty = tid >> 4;

    for (int t = blockIdx.x; t < total; t += gridDim.x) {
        int lo = 0, hi = BB;
        while (lo + 1 < hi) {
            int mid = (lo + hi) >> 1;
            if (pre[mid] <= t) lo = mid; else hi = mid;
        }
        int b = lo;
        int local = t - pre[b];
        int len = max(lengths[b], 1);
        int nt = (len + 127) >> 7;
        int ti = local / nt;
        int tj = local - ti * nt;
        int r0 = ti << 7, c0 = tj << 7;
        const float* base = hn + (size_t)b * NN * DD;
        float acc[8][8] = {};

        for (int kc = 0; kc < DD; kc += KC) {
#pragma unroll
            for (int rr = 0; rr < 128; rr += 32) {
                float4 a = *(const float4*)(base + (size_t)(r0 + lr + rr) * DD + kc + lk);
                As[lk + 0][lr + rr] = a.x; As[lk + 1][lr + rr] = a.y;
                As[lk + 2][lr + rr] = a.z; As[lk + 3][lr + rr] = a.w;
                float4 bb = *(const float4*)(base + (size_t)(c0 + lr + rr) * DD + kc + lk);
                Bs[lk + 0][lr + rr] = bb.x; Bs[lk + 1][lr + rr] = bb.y;
                Bs[lk + 2][lr + rr] = bb.z; Bs[lk + 3][lr + rr] = bb.w;
            }
            __syncthreads();
#pragma unroll
            for (int kk = 0; kk < KC; kk++) {
                float4 a0 = *(const float4*)&As[kk][ty * 8];
                float4 a1 = *(const float4*)&As[kk][ty * 8 + 4];
                float4 b0 = *(const float4*)&Bs[kk][tx * 4];
                float4 b1 = *(const float4*)&Bs[kk][64 + tx * 4];
                float ar[8] = {a0.x, a0.y, a0.z, a0.w, a1.x, a1.y, a1.z, a1.w};
                float bc[8] = {b0.x, b0.y, b0.z, b0.w, b1.x, b1.y, b1.z, b1.w};
#pragma unroll
                for (int r = 0; r < 8; r++)
#pragma unroll
                    for (int c = 0; c < 8; c++)
                        acc[r][c] = fmaf(ar[r], bc[c], acc[r][c]);
            }
            __syncthreads();
        }
        float* out = K + (size_t)b * NN * NN;
#pragma unroll
        for (int r = 0; r < 8; r++) {
            int i = r0 + ty * 8 + r;
            if (i >= len) continue;
#pragma unroll
            for (int cg = 0; cg < 2; cg++) {
                int j0 = c0 + cg * 64 + tx * 4;
                if (j0 >= len) continue;
                float vv[4];
#pragma unroll
                for (int c = 0; c < 4; c++) {
                    float s = acc[r][cg * 4 + c] + ((i == j0 + c) ? 1.0f : 0.0f);
                    vv[c] = expf(2.0f * s - 2.0f);
                }
                float4 o;
                o.x = vv[0]; o.y = vv[1]; o.z = vv[2]; o.w = vv[3];
                *(float4*)(out + (size_t)i * NN + j0) = o;
            }
        }
    }
}

__device__ __forceinline__ float dot8(float4 A, float4 B, float4 x0, float4 x1) {
    float d = fmaf(A.x, x0.x, fmaf(A.y, x0.y, fmaf(A.z, x0.z, A.w * x0.w)));
    return fmaf(B.x, x1.x, fmaf(B.y, x1.y, fmaf(B.z, x1.z, fmaf(B.w, x1.w, d))));
}

// ---------------- persistent Sinkhorn: 20 iters, 1 pass over K per iter ----
// R15 = R11's proven 4-slot/tag exchange + 512-THREAD blocks (regular
// launch; the coop validator that killed R6 is out of the path). Grid 512 x
// 512 thr = 2 blocks/CU x 8 waves = 16 waves/CU (2x R11's TLP); each wave
// now runs only 4 groups of 4 rows -> per-wave critical path halves and
// 4 waves/SIMD interleave over the ~600-900cyc group latency. Accumulation
// order changes vs R11 — PROVEN SAFE by R14 (absmax 0.0, different order).
// XCD swizzle kept from R13 (FETCH 325->270 MB).
__global__ __launch_bounds__(512) void coop_sink(const float* __restrict__ K,
                                                 float* __restrict__ u_buf,
                                                 float* __restrict__ v_buf,
                                                 const int* __restrict__ lengths,
                                                 float* __restrict__ slots) {
    __shared__ float xb[NN];      // current multiplier vector (v)
    __shared__ float pv[8 * NN];  // per-wave column partials (16 KB)

    int g = blockIdx.x;
    int b = (g & 7) | ((g >> 5) << 3);  // batch: same g%8 for all 4 q's
    int q = (g >> 3) & 3;               // quarter within batch
    int len = max(lengths[b], 1);
    int len4 = (len + 3) & ~3;
    int rpq = (len + 3) >> 2;
    int r_lo = q * rpq;
    int nrows = min(len - r_lo, rpq);
    if (nrows < 0) nrows = 0;
    float inv_n = 1.0f / (float)len;

    int tid = threadIdx.x;
    int w = tid >> 6, l = tid & 63;
    int c0 = 4 * l, c1 = 256 + 4 * l;
    bool a0 = c0 < len4, a1 = c1 < len4;
    const float* Kb = K + (size_t)b * NN * NN;

    xb[tid] = (tid < len) ? 1.0f : 0.0f;
    __syncthreads();

    for (int t = 0; t < 20; t++) {
        float4 xv0 = *(const float4*)(xb + c0);
        float4 xv1 = *(const float4*)(xb + c1);
        float4 pa = {0, 0, 0, 0}, pb = {0, 0, 0, 0};

        // ---- phase A: 4-row groups (rows i,i+8,i+16,i+24), wave-stride 32 --
        int i = w;
#pragma unroll 2
        for (; i + 24 < nrows; i += 32) {
            const float* g0 = Kb + (size_t)(r_lo + i) * NN;
            const float* g1 = g0 + (size_t)8 * NN;
            const float* g2 = g0 + (size_t)16 * NN;
            const float* g3 = g0 + (size_t)24 * NN;
            float4 A0 = {0,0,0,0}, A1 = {0,0,0,0}, A2 = {0,0,0,0}, A3 = {0,0,0,0};
            float4 B0 = {0,0,0,0}, B1 = {0,0,0,0}, B2 = {0,0,0,0}, B3 = {0,0,0,0};
            if (a0) {
                A0 = *(const float4*)(g0 + c0); A1 = *(const float4*)(g1 + c0);
                A2 = *(const float4*)(g2 + c0); A3 = *(const float4*)(g3 + c0);
            }
            if (a1) {
                B0 = *(const float4*)(g0 + c1); B1 = *(const float4*)(g1 + c1);
                B2 = *(const float4*)(g2 + c1); B3 = *(const float4*)(g3 + c1);
            }
            float d0 = dot8(A0, B0, xv0, xv1);
            float d1 = dot8(A1, B1, xv0, xv1);
            float d2 = dot8(A2, B2, xv0, xv1);
            float d3 = dot8(A3, B3, xv0, xv1);
#pragma unroll
            for (int m = 32; m; m >>= 1) {  // 4 interleaved butterfly chains
                d0 += __shfl_xor(d0, m);
                d1 += __shfl_xor(d1, m);
                d2 += __shfl_xor(d2, m);
                d3 += __shfl_xor(d3, m);
            }
            float u0 = inv_n / (d0 + 1e-9f), u1 = inv_n / (d1 + 1e-9f);
            float u2 = inv_n / (d2 + 1e-9f), u3 = inv_n / (d3 + 1e-9f);
            pa.x = fmaf(A0.x, u0, fmaf(A1.x, u1, fmaf(A2.x, u2, fmaf(A3.x, u3, pa.x))));
            pa.y = fmaf(A0.y, u0, fmaf(A1.y, u1, fmaf(A2.y, u2, fmaf(A3.y, u3, pa.y))));
            pa.z = fmaf(A0.z, u0, fmaf(A1.z, u1, fmaf(A2.z, u2, fmaf(A3.z, u3, pa.z))));
            pa.w = fmaf(A0.w, u0, fmaf(A1.w, u1, fmaf(A2.w, u2, fmaf(A3.w, u3, pa.w))));
            pb.x = fmaf(B0.x, u0, fmaf(B1.x, u1, fmaf(B2.x, u2, fmaf(B3.x, u3, pb.x))));
            pb.y = fmaf(B0.y, u0, fmaf(B1.y, u1, fmaf(B2.y, u2, fmaf(B3.y, u3, pb.y))));
            pb.z = fmaf(B0.z, u0, fmaf(B1.z, u1, fmaf(B2.z, u2, fmaf(B3.z, u3, pb.z))));
            pb.w = fmaf(B0.w, u0, fmaf(B1.w, u1, fmaf(B2.w, u2, fmaf(B3.w, u3, pb.w))));
            if (t == 19 && l == 0) {
                float* ub = u_buf + (size_t)b * NN + r_lo;
                ub[i] = u0; ub[i + 8] = u1; ub[i + 16] = u2; ub[i + 24] = u3;
            }
        }
        for (; i < nrows; i += 8) {  // remainder rows (same residue set)
            const float* g0 = Kb + (size_t)(r_lo + i) * NN;
            float4 A = {0,0,0,0}, B = {0,0,0,0};
            if (a0) A = *(const float4*)(g0 + c0);
            if (a1) B = *(const float4*)(g0 + c1);
            float d = dot8(A, B, xv0, xv1);
#pragma unroll
            for (int m = 32; m; m >>= 1) d += __shfl_xor(d, m);
            float uu = inv_n / (d + 1e-9f);
            pa.x = fmaf(A.x, uu, pa.x); pa.y = fmaf(A.y, uu, pa.y);
            pa.z = fmaf(A.z, uu, pa.z); pa.w = fmaf(A.w, uu, pa.w);
            pb.x = fmaf(B.x, uu, pb.x); pb.y = fmaf(B.y, uu, pb.y);
            pb.z = fmaf(B.z, uu, pb.z); pb.w = fmaf(B.w, uu, pb.w);
            if (t == 19 && l == 0) u_buf[(size_t)b * NN + r_lo + i] = uu;
        }

        // ---- phase B: reduce 8 waves' partials (LDS), publish slot + tag ---
        *(float4*)(pv + w * NN + c0) = pa;
        *(float4*)(pv + w * NN + c1) = pb;
        __syncthreads();
        float* slotp = slots + ((size_t)(t & 1) * BB * 4 + (size_t)b * 4 + q) * SLOT_STRIDE;
        int c = tid;  // one column per thread
        float s0 = pv[c] + pv[NN + c] + pv[2 * NN + c] + pv[3 * NN + c] +
                   pv[4 * NN + c] + pv[5 * NN + c] + pv[6 * NN + c] + pv[7 * NN + c];
        __hip_atomic_store(slotp + c, s0, __ATOMIC_RELAXED, __HIP_MEMORY_SCOPE_AGENT);
        asm volatile("s_waitcnt vmcnt(0)" ::: "memory");
        __syncthreads();  // all threads' slot stores drained before tag
        if (tid == 0)
            __hip_atomic_store((int*)(slotp + 512), t + 1, __ATOMIC_RELAXED,
                               __HIP_MEMORY_SCOPE_AGENT);
        // ---- barrier: poll the 3 sibling tags (distinct lines, loads only) --
        if (tid < 4 && tid != q) {
            const int* tagp = (const int*)(slots +
                ((size_t)(t & 1) * BB * 4 + (size_t)b * 4 + tid) * SLOT_STRIDE + 512);
            while (__hip_atomic_load(tagp, __ATOMIC_RELAXED, __HIP_MEMORY_SCOPE_AGENT) != t + 1)
                __builtin_amdgcn_s_sleep(1);
        }
        __syncthreads();

        // ---- phase C: v_c = mu/(colsum+eps); own partial stays in regs ----
        const float* sbase = slots + ((size_t)(t & 1) * BB * 4 + (size_t)b * 4) * SLOT_STRIDE;
        int q1 = (q + 1) & 3, q2 = (q + 2) & 3, q3 = (q + 3) & 3;
        float t0 = s0 +
            __hip_atomic_load(sbase + q1 * SLOT_STRIDE + c, __ATOMIC_RELAXED, __HIP_MEMORY_SCOPE_AGENT) +
            __hip_atomic_load(sbase + q2 * SLOT_STRIDE + c, __ATOMIC_RELAXED, __HIP_MEMORY_SCOPE_AGENT) +
            __hip_atomic_load(sbase + q3 * SLOT_STRIDE + c, __ATOMIC_RELAXED, __HIP_MEMORY_SCOPE_AGENT);
        float v0 = (c < len) ? (inv_n / (t0 + 1e-9f)) : 0.0f;
        if (t < 19) {
            xb[c] = v0;
        } else if (c >= r_lo && c < r_lo + nrows) {
            v_buf[(size_t)b * NN + c] = v0;  // owner writes final v
        }
        __syncthreads();
    }
}

// ---------------- kernel 4: fused epilogue, in-place on d_out -------------
__global__ __launch_bounds__(256) void epi_kernel(float* __restrict__ io,
                                                  const float* __restrict__ u,
                                                  const float* __restrict__ v,
                                                  const int* __restrict__ lengths) {
    const float E5 = 0.006737946999085467f;  // exp(-5)
    size_t idx = (size_t)blockIdx.x * 256 + threadIdx.x;  // float4 index
    int b = (int)(idx >> 16);
    int r = (int)(idx >> 7) & (NN - 1);
    int c4 = ((int)idx & 127) << 2;
    int len = max(lengths[b], 1);
    float4 o;
    if (r >= len || c4 >= len) {
        o.x = E5; o.y = E5; o.z = E5; o.w = E5;
        ((float4*)io)[idx] = o;
        return;
    }
    float4 k = ((float4*)io)[idx];
    float ui = u[(size_t)b * NN + r];
    float4 vv = *(const float4*)(v + (size_t)b * NN + c4);
    float t = (float)len * ui;
    float kv[4] = {k.x, k.y, k.z, k.w};
    float vj[4] = {vv.x, vv.y, vv.z, vv.w};
    float ov[4];
#pragma unroll
    for (int c = 0; c < 4; c++) {
        float Kc = kv[c];
        float P = t * Kc * vj[c];
        bool valid = (c4 + c) < len;
        if (valid && P > 0.1f) {
            float x = 2.5f * logf(Kc);  // == 5*sim - 5
            ov[c] = (x > 0.0f) ? (x + 1.0f) : expf(x);
        } else {
            ov[c] = E5;
        }
    }
    o.x = ov[0]; o.y = ov[1]; o.z = ov[2]; o.w = ov[3];
    ((float4*)io)[idx] = o;
}

extern "C" void kernel_launch(void* const* d_in, const int* in_sizes, int n_in,
                              void* d_out, int out_size, void* d_ws, size_t ws_size,
                              hipStream_t stream) {
    const float* h = (const float*)d_in[0];
    const float* W0 = (const float*)d_in[1];
    const float* W1 = (const float*)d_in[2];
    const int* lengths = (const int*)d_in[3];
    float* K = (float*)d_out;  // [B,N,N] K, overwritten in place by epilogue

    char* ws = (char*)d_ws;
    float* hn = (float*)ws;                                   // 33.5 MB
    size_t off = (size_t)BB * NN * DD * 4;
    float* u = (float*)(ws + off);     off += (size_t)BB * NN * 4;                   // 256 KB
    float* v = (float*)(ws + off);     off += (size_t)BB * NN * 4;                   // 256 KB
    float* slots = (float*)(ws + off); off += (size_t)2 * BB * 4 * SLOT_STRIDE * 4;  // 2.2 MB

    hn_kernel<<<BB * NN / 4, 256, 0, stream>>>(h, W0, W1, hn);
    sim_kernel<<<1024, 256, 0, stream>>>(hn, lengths, K);

    // Regular launch: 512 blocks x 512 thr = 2 blocks/CU, 16 waves/CU.
    coop_sink<<<BB * 4, 512, 0, stream>>>(K, u, v, lengths, slots);

    epi_kernel<<<(unsigned)((size_t)BB * NN * NN / 4 / 256), 256, 0, stream>>>(K, u, v, lengths);
}